// Round 1
// baseline (310.623 us; speedup 1.0000x reference)
//
#include <hip/hip_runtime.h>

// Discriminator: conv1(2x2,same)+lrelu -> pad -> LC1(3x3,s(1,2))+lrelu+BN ->
// pad -> LC2(2x2,s1)+lrelu+BN -> pad -> LC3(2x2,s(1,2))+lrelu+BN -> [B,384]
// B=8192. All fp32. BN is train-mode (batch stats over N,H,W).
//
// Decomposition:
//  k0: zero 64-float stats accumulators in ws (ws is poisoned each call).
//  k1: per-position (50) blocks: conv1 recomputed from 4x4 img patch in regs,
//      LC1 via LDS weights [c][k][o16], 2 samples/thread. Writes y1[16*50][B]
//      (post-lrelu, pre-BN) + atomically accumulates BN1 sum/sumsq.
//  k2: per-position (66): BN1 affine applied on load (pad handled by masks),
//      LC2, writes y2[8*66][B] + BN2 stats.
//  k3: per-position (48): BN2 affine on load, LC3, writes y3[8*48][B] + BN3 stats.
//  k4: BN3 affine + LDS tile transpose -> out[B,384].
// Feature-major intermediates => all sample-dim accesses coalesced.
//
// ws layout (floats): [0..63] stats (bn1 sum16/sq16, bn2 sum8/sq8, bn3 sum8/sq8)
//                     [64 ..] y2 (8*66*8192)   [64+4325376 ..] y1 (16*50*8192)
//                     y3 aliases y1 (y1 dead after k2). Total ~41.5 MB.

#define LR(x) ((x) >= 0.0f ? (x) : 0.01f * (x))

__global__ __launch_bounds__(64) void k0_zero(float* __restrict__ stats) {
    stats[threadIdx.x] = 0.0f;
}

__global__ __launch_bounds__(256) void k1_lc1(
    const float* __restrict__ img,   // [8192*90]
    const float* __restrict__ cw,    // conv1_w [64*4]
    const float* __restrict__ cb,    // conv1_b [64]
    const float* __restrict__ lw,    // lc1_w [16*64*450]
    const float* __restrict__ lb,    // lc1_b [16*50]
    float* __restrict__ y1,          // [16*50][8192]
    float* __restrict__ stats)       // [32] sum16, sq16
{
    __shared__ float4 wldv[2304];    // [c64][k9][o16] floats = c*144+k*16+o
    __shared__ float4 w1v[64];       // conv1 w per channel (4 floats)
    __shared__ float  cbl[64];
    __shared__ float  bl[16];
    __shared__ float  red[32];
    float* wld = (float*)wldv;
    float* w1l = (float*)w1v;

    const int pos = blockIdx.x;           // 0..49
    const int oh = pos / 5, ow = pos % 5;
    const int tid = threadIdx.x;

    for (int pair = tid; pair < 1024; pair += 256) {   // pair = o*64+c
        int o = pair >> 6, c = pair & 63;
        const float* src = lw + pair * 450 + pos * 9;
        #pragma unroll
        for (int k = 0; k < 9; k++) wld[c*144 + k*16 + o] = src[k];
    }
    w1l[tid] = cw[tid];
    if (tid < 64) cbl[tid] = cb[tid];
    if (tid < 16) bl[tid] = lb[tid*50 + pos];
    if (tid < 32) red[tid] = 0.0f;
    __syncthreads();

    // lc1 patch tap (i,j): conv1-out coords r=oh+i-1 in [0,10), c2=2ow+j-1 in [0,9)
    float km[9];
    #pragma unroll
    for (int i = 0; i < 3; i++)
        #pragma unroll
        for (int j = 0; j < 3; j++) {
            int r = oh + i - 1, c2 = 2*ow + j - 1;
            km[i*3+j] = (r >= 0 && r < 10 && c2 >= 0 && c2 < 9) ? 1.0f : 0.0f;
        }

    const int s0 = blockIdx.y * 512 + tid;
    const int s1 = s0 + 256;

    // image patch rows oh-1..oh+2, cols 2ow-1..2ow+2 (0 outside 10x9 image)
    float ip[2][16];
    #pragma unroll
    for (int s = 0; s < 2; s++) {
        const float* ib = img + (s == 0 ? s0 : s1) * 90;
        #pragma unroll
        for (int a = 0; a < 4; a++)
            #pragma unroll
            for (int d = 0; d < 4; d++) {
                int r = oh - 1 + a, c2 = 2*ow - 1 + d;
                bool ok = (r >= 0 && r < 10 && c2 >= 0 && c2 < 9);
                ip[s][a*4+d] = ok ? ib[r*9 + c2] : 0.0f;
            }
    }

    float acc[16][2];
    #pragma unroll
    for (int o = 0; o < 16; o++) { acc[o][0] = bl[o]; acc[o][1] = bl[o]; }

    #pragma unroll 1
    for (int c = 0; c < 64; c++) {
        float4 wc = w1v[c];
        float cbias = cbl[c];
        float p[2][9];
        #pragma unroll
        for (int s = 0; s < 2; s++)
            #pragma unroll
            for (int i = 0; i < 3; i++)
                #pragma unroll
                for (int j = 0; j < 3; j++) {
                    float v = cbias + ip[s][i*4+j]     * wc.x + ip[s][i*4+j+1]     * wc.y
                                    + ip[s][(i+1)*4+j] * wc.z + ip[s][(i+1)*4+j+1] * wc.w;
                    v = LR(v);
                    p[s][i*3+j] = v * km[i*3+j];
                }
        const float4* wr = wldv + c*36;
        #pragma unroll
        for (int k = 0; k < 9; k++) {
            float4 wa = wr[k*4+0], wb = wr[k*4+1], wc2 = wr[k*4+2], wd = wr[k*4+3];
            #pragma unroll
            for (int s = 0; s < 2; s++) {
                float pv = p[s][k];
                acc[0][s]  += wa.x*pv;  acc[1][s]  += wa.y*pv;
                acc[2][s]  += wa.z*pv;  acc[3][s]  += wa.w*pv;
                acc[4][s]  += wb.x*pv;  acc[5][s]  += wb.y*pv;
                acc[6][s]  += wb.z*pv;  acc[7][s]  += wb.w*pv;
                acc[8][s]  += wc2.x*pv; acc[9][s]  += wc2.y*pv;
                acc[10][s] += wc2.z*pv; acc[11][s] += wc2.w*pv;
                acc[12][s] += wd.x*pv;  acc[13][s] += wd.y*pv;
                acc[14][s] += wd.z*pv;  acc[15][s] += wd.w*pv;
            }
        }
    }

    #pragma unroll
    for (int o = 0; o < 16; o++) {
        float v0 = LR(acc[o][0]), v1 = LR(acc[o][1]);
        float* dst = y1 + (o*50 + pos) * 8192;
        dst[s0] = v0; dst[s1] = v1;
        float sv = v0 + v1, sq = v0*v0 + v1*v1;
        #pragma unroll
        for (int m = 32; m > 0; m >>= 1) {
            sv += __shfl_xor(sv, m, 64);
            sq += __shfl_xor(sq, m, 64);
        }
        if ((tid & 63) == 0) { atomicAdd(&red[o], sv); atomicAdd(&red[16+o], sq); }
    }
    __syncthreads();
    if (tid < 32) atomicAdd(&stats[tid], red[tid]);
}

__global__ __launch_bounds__(256) void k2_lc2(
    const float* __restrict__ y1,    // [16*50][8192] pre-BN1
    const float* __restrict__ lw,    // lc2_w [8*16*264]
    const float* __restrict__ lb,    // lc2_b [8*66]
    const float* __restrict__ g1, const float* __restrict__ be1,
    float* __restrict__ y2,          // [8*66][8192]
    float* __restrict__ stats)       // stats base
{
    __shared__ float4 wldv[128];     // [c16][k4][o8] floats = c*32+k*8+o
    __shared__ float a1[16], b1[16];
    __shared__ float bl[8];
    __shared__ float red[16];
    float* wld = (float*)wldv;

    const int pos = blockIdx.x;          // 0..65
    const int oh = pos / 6, ow = pos % 6;
    const int tid = threadIdx.x;

    if (tid < 128) {                     // pair = o*16+c
        int o = tid >> 4, c = tid & 15;
        const float* src = lw + tid * 264 + pos * 4;
        #pragma unroll
        for (int k = 0; k < 4; k++) wld[c*32 + k*8 + o] = src[k];
    }
    if (tid < 16) {
        float m = stats[tid] * (1.0f/409600.0f);
        float v = stats[16+tid] * (1.0f/409600.0f) - m*m;
        float a = g1[tid] * rsqrtf(v + 1e-5f);
        a1[tid] = a; b1[tid] = be1[tid] - a*m;
    }
    if (tid < 8) bl[tid] = lb[tid*66 + pos];
    if (tid < 16) red[tid] = 0.0f;
    __syncthreads();

    float km[4];   // r=oh+i-1 in [0,10), c2=ow+j-1 in [0,5)
    #pragma unroll
    for (int i = 0; i < 2; i++)
        #pragma unroll
        for (int j = 0; j < 2; j++) {
            int r = oh + i - 1, c2 = ow + j - 1;
            km[i*2+j] = (r >= 0 && r < 10 && c2 >= 0 && c2 < 5) ? 1.0f : 0.0f;
        }

    const int s0 = blockIdx.y * 512 + tid;
    const int s1 = s0 + 256;

    float acc[8][2];
    #pragma unroll
    for (int o = 0; o < 8; o++) { acc[o][0] = bl[o]; acc[o][1] = bl[o]; }

    #pragma unroll 1
    for (int c = 0; c < 16; c++) {
        float a = a1[c], bb = b1[c];
        float p[2][4];
        #pragma unroll
        for (int i = 0; i < 2; i++)
            #pragma unroll
            for (int j = 0; j < 2; j++) {
                int r = oh + i - 1;  r  = r  < 0 ? 0 : (r  > 9 ? 9 : r);
                int c2 = ow + j - 1; c2 = c2 < 0 ? 0 : (c2 > 4 ? 4 : c2);
                const float* src = y1 + (c*50 + r*5 + c2) * 8192;
                float kmv = km[i*2+j];
                p[0][i*2+j] = kmv * (a * src[s0] + bb);
                p[1][i*2+j] = kmv * (a * src[s1] + bb);
            }
        const float4* wr = wldv + c*8;
        #pragma unroll
        for (int k = 0; k < 4; k++) {
            float4 wa = wr[k*2], wb = wr[k*2+1];
            #pragma unroll
            for (int s = 0; s < 2; s++) {
                float pv = p[s][k];
                acc[0][s] += wa.x*pv; acc[1][s] += wa.y*pv;
                acc[2][s] += wa.z*pv; acc[3][s] += wa.w*pv;
                acc[4][s] += wb.x*pv; acc[5][s] += wb.y*pv;
                acc[6][s] += wb.z*pv; acc[7][s] += wb.w*pv;
            }
        }
    }

    #pragma unroll
    for (int o = 0; o < 8; o++) {
        float v0 = LR(acc[o][0]), v1 = LR(acc[o][1]);
        float* dst = y2 + (o*66 + pos) * 8192;
        dst[s0] = v0; dst[s1] = v1;
        float sv = v0 + v1, sq = v0*v0 + v1*v1;
        #pragma unroll
        for (int m = 32; m > 0; m >>= 1) {
            sv += __shfl_xor(sv, m, 64);
            sq += __shfl_xor(sq, m, 64);
        }
        if ((tid & 63) == 0) { atomicAdd(&red[o], sv); atomicAdd(&red[8+o], sq); }
    }
    __syncthreads();
    if (tid < 16) atomicAdd(&stats[32+tid], red[tid]);
}

__global__ __launch_bounds__(256) void k3_lc3(
    const float* __restrict__ y2,    // [8*66][8192] pre-BN2
    const float* __restrict__ lw,    // lc3_w [8*8*192]
    const float* __restrict__ lb,    // lc3_b [8*48]
    const float* __restrict__ g2, const float* __restrict__ be2,
    float* __restrict__ y3,          // [8*48][8192]
    float* __restrict__ stats)
{
    __shared__ float4 wldv[64];      // [c8][k4][o8] floats = c*32+k*8+o
    __shared__ float a2[8], b2[8];
    __shared__ float bl[8];
    __shared__ float red[16];
    float* wld = (float*)wldv;

    const int pos = blockIdx.x;          // 0..47
    const int oh = pos >> 2, ow = pos & 3;
    const int tid = threadIdx.x;

    if (tid < 64) {                      // pair = o*8+c
        int o = tid >> 3, c = tid & 7;
        const float* src = lw + tid * 192 + pos * 4;
        #pragma unroll
        for (int k = 0; k < 4; k++) wld[c*32 + k*8 + o] = src[k];
    }
    if (tid < 8) {
        float m = stats[32+tid] * (1.0f/540672.0f);
        float v = stats[40+tid] * (1.0f/540672.0f) - m*m;
        float a = g2[tid] * rsqrtf(v + 1e-5f);
        a2[tid] = a; b2[tid] = be2[tid] - a*m;
    }
    if (tid < 8) bl[tid] = lb[tid*48 + pos];
    if (tid < 16) red[tid] = 0.0f;
    __syncthreads();

    float km[4];   // r=oh+i-1 in [0,11), c2=2ow+j-1 in [0,6)
    #pragma unroll
    for (int i = 0; i < 2; i++)
        #pragma unroll
        for (int j = 0; j < 2; j++) {
            int r = oh + i - 1, c2 = 2*ow + j - 1;
            km[i*2+j] = (r >= 0 && r < 11 && c2 >= 0 && c2 < 6) ? 1.0f : 0.0f;
        }

    const int s0 = blockIdx.y * 512 + tid;
    const int s1 = s0 + 256;

    float acc[8][2];
    #pragma unroll
    for (int o = 0; o < 8; o++) { acc[o][0] = bl[o]; acc[o][1] = bl[o]; }

    #pragma unroll 1
    for (int c = 0; c < 8; c++) {
        float a = a2[c], bb = b2[c];
        float p[2][4];
        #pragma unroll
        for (int i = 0; i < 2; i++)
            #pragma unroll
            for (int j = 0; j < 2; j++) {
                int r = oh + i - 1;    r  = r  < 0 ? 0 : (r  > 10 ? 10 : r);
                int c2 = 2*ow + j - 1; c2 = c2 < 0 ? 0 : (c2 > 5 ? 5 : c2);
                const float* src = y2 + (c*66 + r*6 + c2) * 8192;
                float kmv = km[i*2+j];
                p[0][i*2+j] = kmv * (a * src[s0] + bb);
                p[1][i*2+j] = kmv * (a * src[s1] + bb);
            }
        const float4* wr = wldv + c*8;
        #pragma unroll
        for (int k = 0; k < 4; k++) {
            float4 wa = wr[k*2], wb = wr[k*2+1];
            #pragma unroll
            for (int s = 0; s < 2; s++) {
                float pv = p[s][k];
                acc[0][s] += wa.x*pv; acc[1][s] += wa.y*pv;
                acc[2][s] += wa.z*pv; acc[3][s] += wa.w*pv;
                acc[4][s] += wb.x*pv; acc[5][s] += wb.y*pv;
                acc[6][s] += wb.z*pv; acc[7][s] += wb.w*pv;
            }
        }
    }

    #pragma unroll
    for (int o = 0; o < 8; o++) {
        float v0 = LR(acc[o][0]), v1 = LR(acc[o][1]);
        float* dst = y3 + (o*48 + pos) * 8192;
        dst[s0] = v0; dst[s1] = v1;
        float sv = v0 + v1, sq = v0*v0 + v1*v1;
        #pragma unroll
        for (int m = 32; m > 0; m >>= 1) {
            sv += __shfl_xor(sv, m, 64);
            sq += __shfl_xor(sq, m, 64);
        }
        if ((tid & 63) == 0) { atomicAdd(&red[o], sv); atomicAdd(&red[8+o], sq); }
    }
    __syncthreads();
    if (tid < 16) atomicAdd(&stats[48+tid], red[tid]);
}

__global__ __launch_bounds__(256) void k4_out(
    const float* __restrict__ y3,    // [384][8192] pre-BN3
    const float* __restrict__ g3, const float* __restrict__ be3,
    const float* __restrict__ stats,
    float* __restrict__ out)         // [8192][384]
{
    __shared__ float tile[64][65];   // +1 pad: conflict-free transpose
    __shared__ float a3[8], b3[8];
    const int tid = threadIdx.x;
    if (tid < 8) {
        float m = stats[48+tid] * (1.0f/393216.0f);
        float v = stats[56+tid] * (1.0f/393216.0f) - m*m;
        float a = g3[tid] * rsqrtf(v + 1e-5f);
        a3[tid] = a; b3[tid] = be3[tid] - a*m;
    }
    __syncthreads();

    const int fbase = blockIdx.x * 64;   // 6 tiles cover 384 features
    const int sbase = blockIdx.y * 64;   // 128 tiles cover 8192 samples

    #pragma unroll
    for (int rep = 0; rep < 16; rep++) {
        int idx = rep*256 + tid;
        int f = idx >> 6, s = idx & 63;          // lanes: s consecutive -> coalesced
        int ff = fbase + f;
        int o = ff / 48;
        float v = y3[ff*8192 + sbase + s];
        tile[f][s] = a3[o]*v + b3[o];
    }
    __syncthreads();
    #pragma unroll
    for (int rep = 0; rep < 16; rep++) {
        int idx = rep*256 + tid;
        int s = idx >> 6, f = idx & 63;          // lanes: f consecutive -> coalesced
        out[(sbase + s)*384 + fbase + f] = tile[f][s];
    }
}

extern "C" void kernel_launch(void* const* d_in, const int* in_sizes, int n_in,
                              void* d_out, int out_size, void* d_ws, size_t ws_size,
                              hipStream_t stream) {
    const float* image   = (const float*)d_in[0];
    const float* conv1_w = (const float*)d_in[1];
    const float* conv1_b = (const float*)d_in[2];
    const float* lc1_w   = (const float*)d_in[3];
    const float* lc1_b   = (const float*)d_in[4];
    const float* lc2_w   = (const float*)d_in[5];
    const float* lc2_b   = (const float*)d_in[6];
    const float* lc3_w   = (const float*)d_in[7];
    const float* lc3_b   = (const float*)d_in[8];
    const float* gamma1  = (const float*)d_in[9];
    const float* beta1   = (const float*)d_in[10];
    const float* gamma2  = (const float*)d_in[11];
    const float* beta2   = (const float*)d_in[12];
    const float* gamma3  = (const float*)d_in[13];
    const float* beta3   = (const float*)d_in[14];

    float* ws    = (float*)d_ws;
    float* stats = ws;                       // 64 floats
    float* y2    = ws + 64;                  // 8*66*8192  = 4,325,376
    float* y1    = ws + 64 + 4325376;        // 16*50*8192 = 6,553,600
    float* y3    = y1;                       // alias: y1 dead after k2

    k0_zero<<<dim3(1),  dim3(64),  0, stream>>>(stats);
    k1_lc1 <<<dim3(50, 16), dim3(256), 0, stream>>>(image, conv1_w, conv1_b,
                                                    lc1_w, lc1_b, y1, stats);
    k2_lc2 <<<dim3(66, 16), dim3(256), 0, stream>>>(y1, lc2_w, lc2_b,
                                                    gamma1, beta1, y2, stats);
    k3_lc3 <<<dim3(48, 16), dim3(256), 0, stream>>>(y2, lc3_w, lc3_b,
                                                    gamma2, beta2, y3, stats);
    k4_out <<<dim3(6, 128), dim3(256), 0, stream>>>(y3, gamma3, beta3, stats,
                                                    (float*)d_out);
}

// Round 2
// 193.026 us; speedup vs baseline: 1.6092x; 1.6092x over previous
//
#include <hip/hip_runtime.h>

// Discriminator: conv1(2x2,same)+lrelu -> pad -> LC1(3x3,s(1,2))+lrelu+BN ->
// pad -> LC2(2x2,s1)+lrelu+BN -> pad -> LC3(2x2,s(1,2))+lrelu+BN -> [B,384]
// B=8192. BN train-mode (batch stats).
//
// R1: k1 rewritten as bf16 MFMA GEMM per position:
//   C[16o x s] = W[16o x K] * P[K x s], K = tap-loop(9) x 2 chunks of 32 ch.
//   A-frag = lc1 weights (bf16, precomputed by kB into ws, staged to LDS,
//   ONE ds_read_b128 per (tap,chunk) per wave -- kills the LDS-broadcast
//   bottleneck that made R0's k1 183us). B-frag = conv1 patches computed
//   on the fly in regs (6 VALU/val) packed bf16 via v_perm_b32. fp32 accum.
//   k2/k3: 4 samples/thread (was 2) -> halves weight ds_read per FMA.

#define LR(x) ((x) >= 0.0f ? (x) : 0.01f * (x))

typedef float f32x4 __attribute__((ext_vector_type(4)));
typedef short bf16x8 __attribute__((ext_vector_type(8)));

union FR { int4 i4; bf16x8 bf; unsigned u[4]; };

// pack two fp32 -> packed bf16 (truncation) in ONE v_perm_b32
static __device__ inline unsigned pk2(float hi, float lo) {
    return __builtin_amdgcn_perm(__float_as_uint(hi), __float_as_uint(lo), 0x07060302u);
}
// RNE fp32->bf16 (for weights, done once in kB)
static __device__ inline unsigned bfr(float f) {
    unsigned u = __float_as_uint(f);
    return (u + 0x7fffu + ((u >> 16) & 1u)) >> 16;
}

__global__ __launch_bounds__(64) void k0_zero(float* __restrict__ stats) {
    stats[threadIdx.x] = 0.0f;
}

// Precompute A-fragments (lc1 weights, bf16) for all 50 positions.
// Layout: afg[pos*1152 + (h*9+t)*64 + lane] = int4 of 8 bf16:
//   element j of lane l: W[o = l&15][c = 32h + 8*(l>>4) + j][tap t]
__global__ __launch_bounds__(256) void kB_wfrag(
    const float* __restrict__ lw,    // lc1_w [16][64][450]
    int4* __restrict__ afg)
{
    const int pos = blockIdx.x;
    const int tid = threadIdx.x;
    for (int e = tid; e < 1152; e += 256) {
        int l = e & 63, ht = e >> 6;
        int h = ht / 9, t = ht - 9 * h;
        int q = l >> 4, o = l & 15;
        unsigned uu[4];
        #pragma unroll
        for (int jj = 0; jj < 4; ++jj) {
            int c0 = 32 * h + 8 * q + 2 * jj;
            float w0 = lw[(o * 64 + c0) * 450 + pos * 9 + t];
            float w1 = lw[(o * 64 + c0 + 1) * 450 + pos * 9 + t];
            uu[jj] = bfr(w0) | (bfr(w1) << 16);
        }
        int4 st = { (int)uu[0], (int)uu[1], (int)uu[2], (int)uu[3] };
        afg[pos * 1152 + e] = st;
    }
}

__global__ __launch_bounds__(256) void k1_lc1(
    const float* __restrict__ img,   // [8192*90]
    const float* __restrict__ cw,    // conv1_w [64*4]
    const float* __restrict__ cb,    // conv1_b [64]
    const int4* __restrict__ afg,    // precomputed weight frags
    const float* __restrict__ lb,    // lc1_b [16*50]
    float* __restrict__ y1,          // [16*50][8192]
    float* __restrict__ stats)       // [32] sum16, sq16
{
    __shared__ int4   AfL[1152];     // weight frags for this pos (18432 B)
    __shared__ float4 cw4s[64];
    __shared__ float  cbl[64];
    __shared__ float  bl[16];
    __shared__ float  red[32];

    const int pos = blockIdx.x;           // 0..49
    const int oh = pos / 5, ow = pos % 5;
    const int tid = threadIdx.x;
    const int wv = tid >> 6, lane = tid & 63;
    const int lane15 = lane & 15, q = lane >> 4;

    for (int e = tid; e < 1152; e += 256) AfL[e] = afg[pos * 1152 + e];
    if (tid < 64) { cw4s[tid] = ((const float4*)cw)[tid]; cbl[tid] = cb[tid]; }
    if (tid < 16) bl[tid] = lb[tid * 50 + pos];
    if (tid < 32) red[tid] = 0.0f;
    __syncthreads();

    // valid-tap mask (block-uniform)
    bool km[9];
    #pragma unroll
    for (int i = 0; i < 3; i++)
        #pragma unroll
        for (int j = 0; j < 3; j++) {
            int r = oh + i - 1, c2 = 2 * ow + j - 1;
            km[i * 3 + j] = (r >= 0 && r < 10 && c2 >= 0 && c2 < 9);
        }

    // image patches: 4 sample-groups, 4x4 window (rows oh-1..+2, cols 2ow-1..+2)
    const int sBase = blockIdx.y * 256 + wv * 64;
    float ip[4][16];
    #pragma unroll
    for (int g = 0; g < 4; ++g) {
        const float* ib = img + (size_t)(sBase + g * 16 + lane15) * 90;
        #pragma unroll
        for (int a = 0; a < 4; ++a) {
            int r = oh - 1 + a;
            bool rok = (r >= 0 && r < 10);
            #pragma unroll
            for (int d = 0; d < 4; ++d) {
                int c2 = 2 * ow - 1 + d;
                bool ok = rok && (c2 >= 0 && c2 < 9);
                ip[g][a * 4 + d] = ok ? ib[r * 9 + c2] : 0.0f;
            }
        }
    }

    f32x4 acc[4];
    #pragma unroll
    for (int g = 0; g < 4; ++g) acc[g] = (f32x4){0.f, 0.f, 0.f, 0.f};

    #pragma unroll
    for (int h = 0; h < 2; ++h) {
        // conv1 weights for this lane's 8 channels (32h+8q .. +8)
        float4 wcr[8]; float cbr[8];
        #pragma unroll
        for (int cc = 0; cc < 8; ++cc) {
            wcr[cc] = cw4s[h * 32 + q * 8 + cc];
            cbr[cc] = cbl[h * 32 + q * 8 + cc];
        }
        #pragma unroll
        for (int t = 0; t < 9; ++t) {
            const int ti = t / 3, tj = t % 3;
            const int i0 = ti * 4 + tj;
            if (km[t]) {
                FR fa; fa.i4 = AfL[(h * 9 + t) * 64 + lane];
                #pragma unroll
                for (int g = 0; g < 4; ++g) {
                    float p[8];
                    #pragma unroll
                    for (int cc = 0; cc < 8; ++cc) {
                        float4 wc = wcr[cc];
                        float v = cbr[cc];
                        v = fmaf(ip[g][i0],     wc.x, v);
                        v = fmaf(ip[g][i0 + 1], wc.y, v);
                        v = fmaf(ip[g][i0 + 4], wc.z, v);
                        v = fmaf(ip[g][i0 + 5], wc.w, v);
                        p[cc] = fmaxf(v, 0.01f * v);     // lrelu
                    }
                    FR fb;
                    fb.u[0] = pk2(p[1], p[0]);
                    fb.u[1] = pk2(p[3], p[2]);
                    fb.u[2] = pk2(p[5], p[4]);
                    fb.u[3] = pk2(p[7], p[6]);
                    acc[g] = __builtin_amdgcn_mfma_f32_16x16x32_bf16(fa.bf, fb.bf, acc[g], 0, 0, 0);
                }
            }
        }
    }

    // epilogue: +bias, lrelu, store y1, BN1 stats
    float so[4], sq[4];
    #pragma unroll
    for (int r = 0; r < 4; ++r) { so[r] = 0.f; sq[r] = 0.f; }
    #pragma unroll
    for (int g = 0; g < 4; ++g) {
        #pragma unroll
        for (int r = 0; r < 4; ++r) {
            int o = q * 4 + r;
            float v = acc[g][r] + bl[o];
            v = fmaxf(v, 0.01f * v);
            y1[(size_t)(o * 50 + pos) * 8192 + sBase + g * 16 + lane15] = v;
            so[r] += v; sq[r] += v * v;
        }
    }
    #pragma unroll
    for (int r = 0; r < 4; ++r) {
        #pragma unroll
        for (int m = 1; m < 16; m <<= 1) {
            so[r] += __shfl_xor(so[r], m, 16);
            sq[r] += __shfl_xor(sq[r], m, 16);
        }
        if (lane15 == 0) {
            int o = q * 4 + r;
            atomicAdd(&red[o], so[r]);
            atomicAdd(&red[16 + o], sq[r]);
        }
    }
    __syncthreads();
    if (tid < 32) atomicAdd(&stats[tid], red[tid]);
}

__global__ __launch_bounds__(256) void k2_lc2(
    const float* __restrict__ y1,    // [16*50][8192] pre-BN1
    const float* __restrict__ lw,    // lc2_w [8*16*264]
    const float* __restrict__ lb,    // lc2_b [8*66]
    const float* __restrict__ g1, const float* __restrict__ be1,
    float* __restrict__ y2,          // [8*66][8192]
    float* __restrict__ stats)
{
    __shared__ float4 wldv[128];     // [c16][k4][o8] floats = c*32+k*8+o
    __shared__ float a1[16], b1[16];
    __shared__ float bl[8];
    __shared__ float red[16];
    float* wld = (float*)wldv;

    const int pos = blockIdx.x;          // 0..65
    const int oh = pos / 6, ow = pos % 6;
    const int tid = threadIdx.x;

    if (tid < 128) {                     // pair = o*16+c
        const float* src = lw + tid * 264 + pos * 4;
        int o = tid >> 4, c = tid & 15;
        #pragma unroll
        for (int k = 0; k < 4; k++) wld[c * 32 + k * 8 + o] = src[k];
    }
    if (tid < 16) {
        float m = stats[tid] * (1.0f / 409600.0f);
        float v = stats[16 + tid] * (1.0f / 409600.0f) - m * m;
        float a = g1[tid] * rsqrtf(v + 1e-5f);
        a1[tid] = a; b1[tid] = be1[tid] - a * m;
    }
    if (tid < 8) bl[tid] = lb[tid * 66 + pos];
    if (tid < 16) red[tid] = 0.0f;
    __syncthreads();

    float km[4];
    #pragma unroll
    for (int i = 0; i < 2; i++)
        #pragma unroll
        for (int j = 0; j < 2; j++) {
            int r = oh + i - 1, c2 = ow + j - 1;
            km[i * 2 + j] = (r >= 0 && r < 10 && c2 >= 0 && c2 < 5) ? 1.0f : 0.0f;
        }

    const int sb = blockIdx.y * 1024 + tid;    // 4 samples: sb + 256*s

    float acc[8][4];
    #pragma unroll
    for (int o = 0; o < 8; o++)
        #pragma unroll
        for (int s = 0; s < 4; s++) acc[o][s] = bl[o];

    #pragma unroll 1
    for (int c = 0; c < 16; c++) {
        float a = a1[c], bb = b1[c];
        float p[4][4];                       // [tap][sample]
        #pragma unroll
        for (int i = 0; i < 2; i++)
            #pragma unroll
            for (int j = 0; j < 2; j++) {
                int r = oh + i - 1;  r = r < 0 ? 0 : (r > 9 ? 9 : r);
                int c2 = ow + j - 1; c2 = c2 < 0 ? 0 : (c2 > 4 ? 4 : c2);
                const float* src = y1 + (size_t)(c * 50 + r * 5 + c2) * 8192 + sb;
                float kmv = km[i * 2 + j];
                #pragma unroll
                for (int s = 0; s < 4; s++)
                    p[i * 2 + j][s] = kmv * fmaf(a, src[s * 256], bb);
            }
        const float4* wr = wldv + c * 8;
        #pragma unroll
        for (int k = 0; k < 4; k++) {
            float4 wa = wr[k * 2], wb = wr[k * 2 + 1];
            #pragma unroll
            for (int s = 0; s < 4; s++) {
                float pv = p[k][s];
                acc[0][s] += wa.x * pv; acc[1][s] += wa.y * pv;
                acc[2][s] += wa.z * pv; acc[3][s] += wa.w * pv;
                acc[4][s] += wb.x * pv; acc[5][s] += wb.y * pv;
                acc[6][s] += wb.z * pv; acc[7][s] += wb.w * pv;
            }
        }
    }

    #pragma unroll
    for (int o = 0; o < 8; o++) {
        float sv = 0.f, sqv = 0.f;
        float* dst = y2 + (size_t)(o * 66 + pos) * 8192 + sb;
        #pragma unroll
        for (int s = 0; s < 4; s++) {
            float v = LR(acc[o][s]);
            dst[s * 256] = v;
            sv += v; sqv += v * v;
        }
        #pragma unroll
        for (int m = 32; m > 0; m >>= 1) {
            sv  += __shfl_xor(sv, m, 64);
            sqv += __shfl_xor(sqv, m, 64);
        }
        if ((tid & 63) == 0) { atomicAdd(&red[o], sv); atomicAdd(&red[8 + o], sqv); }
    }
    __syncthreads();
    if (tid < 16) atomicAdd(&stats[32 + tid], red[tid]);
}

__global__ __launch_bounds__(256) void k3_lc3(
    const float* __restrict__ y2,    // [8*66][8192] pre-BN2
    const float* __restrict__ lw,    // lc3_w [8*8*192]
    const float* __restrict__ lb,    // lc3_b [8*48]
    const float* __restrict__ g2, const float* __restrict__ be2,
    float* __restrict__ y3,          // [8*48][8192]
    float* __restrict__ stats)
{
    __shared__ float4 wldv[64];      // [c8][k4][o8]
    __shared__ float a2[8], b2[8];
    __shared__ float bl[8];
    __shared__ float red[16];
    float* wld = (float*)wldv;

    const int pos = blockIdx.x;          // 0..47
    const int oh = pos >> 2, ow = pos & 3;
    const int tid = threadIdx.x;

    if (tid < 64) {                      // pair = o*8+c
        const float* src = lw + tid * 192 + pos * 4;
        int o = tid >> 3, c = tid & 7;
        #pragma unroll
        for (int k = 0; k < 4; k++) wld[c * 32 + k * 8 + o] = src[k];
    }
    if (tid < 8) {
        float m = stats[32 + tid] * (1.0f / 540672.0f);
        float v = stats[40 + tid] * (1.0f / 540672.0f) - m * m;
        float a = g2[tid] * rsqrtf(v + 1e-5f);
        a2[tid] = a; b2[tid] = be2[tid] - a * m;
    }
    if (tid < 8) bl[tid] = lb[tid * 48 + pos];
    if (tid < 16) red[tid] = 0.0f;
    __syncthreads();

    float km[4];
    #pragma unroll
    for (int i = 0; i < 2; i++)
        #pragma unroll
        for (int j = 0; j < 2; j++) {
            int r = oh + i - 1, c2 = 2 * ow + j - 1;
            km[i * 2 + j] = (r >= 0 && r < 11 && c2 >= 0 && c2 < 6) ? 1.0f : 0.0f;
        }

    const int sb = blockIdx.y * 1024 + tid;

    float acc[8][4];
    #pragma unroll
    for (int o = 0; o < 8; o++)
        #pragma unroll
        for (int s = 0; s < 4; s++) acc[o][s] = bl[o];

    #pragma unroll 1
    for (int c = 0; c < 8; c++) {
        float a = a2[c], bb = b2[c];
        float p[4][4];
        #pragma unroll
        for (int i = 0; i < 2; i++)
            #pragma unroll
            for (int j = 0; j < 2; j++) {
                int r = oh + i - 1;      r = r < 0 ? 0 : (r > 10 ? 10 : r);
                int c2 = 2 * ow + j - 1; c2 = c2 < 0 ? 0 : (c2 > 5 ? 5 : c2);
                const float* src = y2 + (size_t)(c * 66 + r * 6 + c2) * 8192 + sb;
                float kmv = km[i * 2 + j];
                #pragma unroll
                for (int s = 0; s < 4; s++)
                    p[i * 2 + j][s] = kmv * fmaf(a, src[s * 256], bb);
            }
        const float4* wr = wldv + c * 8;
        #pragma unroll
        for (int k = 0; k < 4; k++) {
            float4 wa = wr[k * 2], wb = wr[k * 2 + 1];
            #pragma unroll
            for (int s = 0; s < 4; s++) {
                float pv = p[k][s];
                acc[0][s] += wa.x * pv; acc[1][s] += wa.y * pv;
                acc[2][s] += wa.z * pv; acc[3][s] += wa.w * pv;
                acc[4][s] += wb.x * pv; acc[5][s] += wb.y * pv;
                acc[6][s] += wb.z * pv; acc[7][s] += wb.w * pv;
            }
        }
    }

    #pragma unroll
    for (int o = 0; o < 8; o++) {
        float sv = 0.f, sqv = 0.f;
        float* dst = y3 + (size_t)(o * 48 + pos) * 8192 + sb;
        #pragma unroll
        for (int s = 0; s < 4; s++) {
            float v = LR(acc[o][s]);
            dst[s * 256] = v;
            sv += v; sqv += v * v;
        }
        #pragma unroll
        for (int m = 32; m > 0; m >>= 1) {
            sv  += __shfl_xor(sv, m, 64);
            sqv += __shfl_xor(sqv, m, 64);
        }
        if ((tid & 63) == 0) { atomicAdd(&red[o], sv); atomicAdd(&red[8 + o], sqv); }
    }
    __syncthreads();
    if (tid < 16) atomicAdd(&stats[48 + tid], red[tid]);
}

__global__ __launch_bounds__(256) void k4_out(
    const float* __restrict__ y3,    // [384][8192] pre-BN3
    const float* __restrict__ g3, const float* __restrict__ be3,
    const float* __restrict__ stats,
    float* __restrict__ out)         // [8192][384]
{
    __shared__ float tile[64][65];
    __shared__ float a3[8], b3[8];
    const int tid = threadIdx.x;
    if (tid < 8) {
        float m = stats[48 + tid] * (1.0f / 393216.0f);
        float v = stats[56 + tid] * (1.0f / 393216.0f) - m * m;
        float a = g3[tid] * rsqrtf(v + 1e-5f);
        a3[tid] = a; b3[tid] = be3[tid] - a * m;
    }
    __syncthreads();

    const int fbase = blockIdx.x * 64;
    const int sbase = blockIdx.y * 64;

    #pragma unroll
    for (int rep = 0; rep < 16; rep++) {
        int idx = rep * 256 + tid;
        int f = idx >> 6, s = idx & 63;
        int ff = fbase + f;
        int o = ff / 48;
        float v = y3[(size_t)ff * 8192 + sbase + s];
        tile[f][s] = a3[o] * v + b3[o];
    }
    __syncthreads();
    #pragma unroll
    for (int rep = 0; rep < 16; rep++) {
        int idx = rep * 256 + tid;
        int s = idx >> 6, f = idx & 63;
        out[(size_t)(sbase + s) * 384 + fbase + f] = tile[f][s];
    }
}

extern "C" void kernel_launch(void* const* d_in, const int* in_sizes, int n_in,
                              void* d_out, int out_size, void* d_ws, size_t ws_size,
                              hipStream_t stream) {
    const float* image   = (const float*)d_in[0];
    const float* conv1_w = (const float*)d_in[1];
    const float* conv1_b = (const float*)d_in[2];
    const float* lc1_w   = (const float*)d_in[3];
    const float* lc1_b   = (const float*)d_in[4];
    const float* lc2_w   = (const float*)d_in[5];
    const float* lc2_b   = (const float*)d_in[6];
    const float* lc3_w   = (const float*)d_in[7];
    const float* lc3_b   = (const float*)d_in[8];
    const float* gamma1  = (const float*)d_in[9];
    const float* beta1   = (const float*)d_in[10];
    const float* gamma2  = (const float*)d_in[11];
    const float* beta2   = (const float*)d_in[12];
    const float* gamma3  = (const float*)d_in[13];
    const float* beta3   = (const float*)d_in[14];

    float* ws    = (float*)d_ws;
    float* stats = ws;                               // 64 floats
    float* y2    = ws + 64;                          // 8*66*8192  = 4,325,376
    float* y1    = ws + 64 + 4325376;                // 16*50*8192 = 6,553,600
    float* y3    = y1;                               // alias (y1 dead after k2)
    int4*  afg   = (int4*)(ws + 64 + 4325376 + 6553600);  // 50*1152 int4 = 921.6 KB

    k0_zero <<<dim3(1),       dim3(64),  0, stream>>>(stats);
    kB_wfrag<<<dim3(50),      dim3(256), 0, stream>>>(lc1_w, afg);
    k1_lc1  <<<dim3(50, 32),  dim3(256), 0, stream>>>(image, conv1_w, conv1_b,
                                                      afg, lc1_b, y1, stats);
    k2_lc2  <<<dim3(66, 8),   dim3(256), 0, stream>>>(y1, lc2_w, lc2_b,
                                                      gamma1, beta1, y2, stats);
    k3_lc3  <<<dim3(48, 8),   dim3(256), 0, stream>>>(y2, lc3_w, lc3_b,
                                                      gamma2, beta2, y3, stats);
    k4_out  <<<dim3(6, 128),  dim3(256), 0, stream>>>(y3, gamma3, beta3, stats,
                                                      (float*)d_out);
}